// Round 1
// baseline (1885.296 us; speedup 1.0000x reference)
//
#include <hip/hip_runtime.h>
#include <math.h>

#define NH     12
#define DH     64
#define WIN    32
#define SEQL   1024
#define BSZ    2
#define NW     (SEQL / WIN)       // 32
#define DMODEL 768
#define NCOL   (5 * NH * DH)      // 3840

// ---------------------------------------------------------------------------
// fp32 tiled GEMM with bias: C[M][N] = A[M][K] @ B[K][N] + bias[N]
// 128x128 tile, 256 threads, 8x8 per thread, BK=8. M,N % 128 == 0, K % 8 == 0.
// ---------------------------------------------------------------------------
template<int BM, int BN, int BK>
__global__ __launch_bounds__(256)
void gemm_bias_kernel(const float* __restrict__ A, const float* __restrict__ B,
                      const float* __restrict__ bias, float* __restrict__ C,
                      int M, int N, int K) {
  __shared__ float As[BK][BM];
  __shared__ float Bs[BK][BN];
  const int tid = threadIdx.x;
  const int bm = blockIdx.y * BM;
  const int bn = blockIdx.x * BN;
  const int tm = (tid >> 4) << 3;
  const int tn = (tid & 15) << 3;
  float acc[8][8] = {};
  for (int k0 = 0; k0 < K; k0 += BK) {
    {
      const int m  = tid >> 1;          // 0..127
      const int kq = (tid & 1) << 2;    // 0 or 4
      const float4 v = *reinterpret_cast<const float4*>(&A[(size_t)(bm + m) * K + k0 + kq]);
      As[kq + 0][m] = v.x; As[kq + 1][m] = v.y;
      As[kq + 2][m] = v.z; As[kq + 3][m] = v.w;
    }
    {
      const int kq = tid >> 5;          // 0..7
      const int nn = (tid & 31) << 2;   // 0..124
      *reinterpret_cast<float4*>(&Bs[kq][nn]) =
          *reinterpret_cast<const float4*>(&B[(size_t)(k0 + kq) * N + bn + nn]);
    }
    __syncthreads();
#pragma unroll
    for (int kk = 0; kk < BK; ++kk) {
      float ar[8], br[8];
      *reinterpret_cast<float4*>(&ar[0]) = *reinterpret_cast<const float4*>(&As[kk][tm]);
      *reinterpret_cast<float4*>(&ar[4]) = *reinterpret_cast<const float4*>(&As[kk][tm + 4]);
      *reinterpret_cast<float4*>(&br[0]) = *reinterpret_cast<const float4*>(&Bs[kk][tn]);
      *reinterpret_cast<float4*>(&br[4]) = *reinterpret_cast<const float4*>(&Bs[kk][tn + 4]);
#pragma unroll
      for (int i = 0; i < 8; ++i)
#pragma unroll
        for (int j = 0; j < 8; ++j)
          acc[i][j] = fmaf(ar[i], br[j], acc[i][j]);
    }
    __syncthreads();
  }
#pragma unroll
  for (int i = 0; i < 8; ++i) {
#pragma unroll
    for (int j = 0; j < 8; ++j) {
      const int ncol = bn + tn + j;
      C[(size_t)(bm + tm + i) * N + ncol] = acc[i][j] + bias[ncol];
    }
  }
}

// ---------------------------------------------------------------------------
// Local trittention core. One block per (window n, batch*head bh).
// 256 threads = 4 waves; wave w handles queries i = w*8 .. w*8+7.
// Lane j (0..63) owns look-around row j. Scores s[j][k] = sum_d c_i*a_j*b_k.
// z[i,:] = sum_j rowsum_j * d[j,:] + sum_{j,k} e[j][k] * e_la[k,:], / total.
// valid(j,k): k > j && k <= i+32 && (n>0 || (j>=32 && k>=32)).
// Degenerate row (n==0,i==0): no valid entries -> uniform 1/4096 over ALL.
// ---------------------------------------------------------------------------
__global__ __launch_bounds__(256, 2)
void attn_kernel(const float* __restrict__ Y, float* __restrict__ Z) {
  __shared__ float aT[DH][64];   // aT[d][j]  (transposed: per-lane reads conflict-free)
  __shared__ float dT[DH][64];   // dT[d][j]
  __shared__ float b_s[64][DH];  // row-major (read broadcast per k)
  __shared__ float e_s[64][DH];  // row-major (read broadcast per k)

  const int n  = blockIdx.x;     // window
  const int bh = blockIdx.y;     // batch*head
  const int bi = bh / NH;
  const int h  = bh % NH;
  const int tid  = threadIdx.x;
  const int wave = tid >> 6;
  const int lane = tid & 63;

  const float* Yb = Y + (size_t)bi * SEQL * NCOL;

  // ---- stage look-around tiles (rows t = n*32-32+r, r=0..63; t<0 -> zeros)
  {
    const int r    = tid >> 2;          // 0..63
    const int dq16 = (tid & 3) << 4;    // 0,16,32,48
    const int t    = n * WIN - WIN + r;
    if (t >= 0) {
      const float* rowp = Yb + (size_t)t * NCOL + h * DH;
#pragma unroll
      for (int e4 = 0; e4 < 16; e4 += 4) {
        const float4 va = *reinterpret_cast<const float4*>(rowp + 0 * (NH * DH) + dq16 + e4);
        aT[dq16 + e4 + 0][r] = va.x; aT[dq16 + e4 + 1][r] = va.y;
        aT[dq16 + e4 + 2][r] = va.z; aT[dq16 + e4 + 3][r] = va.w;
        *reinterpret_cast<float4*>(&b_s[r][dq16 + e4]) =
            *reinterpret_cast<const float4*>(rowp + 1 * (NH * DH) + dq16 + e4);
        const float4 vd = *reinterpret_cast<const float4*>(rowp + 3 * (NH * DH) + dq16 + e4);
        dT[dq16 + e4 + 0][r] = vd.x; dT[dq16 + e4 + 1][r] = vd.y;
        dT[dq16 + e4 + 2][r] = vd.z; dT[dq16 + e4 + 3][r] = vd.w;
        *reinterpret_cast<float4*>(&e_s[r][dq16 + e4]) =
            *reinterpret_cast<const float4*>(rowp + 4 * (NH * DH) + dq16 + e4);
      }
    } else {
      const float4 zz = make_float4(0.f, 0.f, 0.f, 0.f);
#pragma unroll
      for (int e4 = 0; e4 < 16; e4 += 4) {
        aT[dq16 + e4 + 0][r] = 0.f; aT[dq16 + e4 + 1][r] = 0.f;
        aT[dq16 + e4 + 2][r] = 0.f; aT[dq16 + e4 + 3][r] = 0.f;
        *reinterpret_cast<float4*>(&b_s[r][dq16 + e4]) = zz;
        dT[dq16 + e4 + 0][r] = 0.f; dT[dq16 + e4 + 1][r] = 0.f;
        dT[dq16 + e4 + 2][r] = 0.f; dT[dq16 + e4 + 3][r] = 0.f;
        *reinterpret_cast<float4*>(&e_s[r][dq16 + e4]) = zz;
      }
    }
  }
  __syncthreads();

  const bool rowOk = (n > 0) || (lane >= 32);
  const int  kmin  = (n > 0) ? 1 : 32;   // below this k is never valid
  const float NEG_INF = -__builtin_inff();

  for (int ii = 0; ii < 8; ++ii) {
    const int i = wave * 8 + ii;

    // u[d] = c[i][d] * a[lane][d]   (c read from global: broadcast, L1/L2-cached)
    const float* crow = Yb + (size_t)(n * WIN + i) * NCOL + (2 * NH + h) * DH;
    float u[64];
#pragma unroll
    for (int dq = 0; dq < 64; dq += 4) {
      const float4 cv = *reinterpret_cast<const float4*>(crow + dq);
      u[dq + 0] = cv.x * aT[dq + 0][lane];
      u[dq + 1] = cv.y * aT[dq + 1][lane];
      u[dq + 2] = cv.z * aT[dq + 2][lane];
      u[dq + 3] = cv.w * aT[dq + 3][lane];
    }

    auto score_at = [&](int k) -> float {
      float s0 = 0.f, s1 = 0.f, s2 = 0.f, s3 = 0.f;
#pragma unroll
      for (int dq = 0; dq < 64; dq += 16) {
        const float4 b0 = *reinterpret_cast<const float4*>(&b_s[k][dq + 0]);
        const float4 b1 = *reinterpret_cast<const float4*>(&b_s[k][dq + 4]);
        const float4 b2 = *reinterpret_cast<const float4*>(&b_s[k][dq + 8]);
        const float4 b3 = *reinterpret_cast<const float4*>(&b_s[k][dq + 12]);
        s0 = fmaf(u[dq + 0],  b0.x, s0); s0 = fmaf(u[dq + 1],  b0.y, s0);
        s0 = fmaf(u[dq + 2],  b0.z, s0); s0 = fmaf(u[dq + 3],  b0.w, s0);
        s1 = fmaf(u[dq + 4],  b1.x, s1); s1 = fmaf(u[dq + 5],  b1.y, s1);
        s1 = fmaf(u[dq + 6],  b1.z, s1); s1 = fmaf(u[dq + 7],  b1.w, s1);
        s2 = fmaf(u[dq + 8],  b2.x, s2); s2 = fmaf(u[dq + 9],  b2.y, s2);
        s2 = fmaf(u[dq + 10], b2.z, s2); s2 = fmaf(u[dq + 11], b2.w, s2);
        s3 = fmaf(u[dq + 12], b3.x, s3); s3 = fmaf(u[dq + 13], b3.y, s3);
        s3 = fmaf(u[dq + 14], b3.z, s3); s3 = fmaf(u[dq + 15], b3.w, s3);
      }
      return (s0 + s1) + (s2 + s3);
    };

    const int kmax = i + 32;  // inclusive

    // ---- pass 1: row max over valid entries
    float mrow = NEG_INF;
    for (int k = kmin; k < 64; ++k) {
      const float s = score_at(k);
      const bool valid = (k > lane) && (k <= kmax) && rowOk;
      if (valid) mrow = fmaxf(mrow, s);
    }
#pragma unroll
    for (int off = 32; off >= 1; off >>= 1)
      mrow = fmaxf(mrow, __shfl_xor(mrow, off));

    // ---- pass 2: exp + marginal accumulation
    float z[64];
#pragma unroll
    for (int dq = 0; dq < 64; ++dq) z[dq] = 0.f;
    float rowsum = 0.f;

    if (mrow == NEG_INF) {
      // degenerate (n==0, i==0): softmax uniform over ALL 4096 entries
      rowsum = 64.f;
      for (int k = 0; k < 64; ++k) {
#pragma unroll
        for (int dq = 0; dq < 64; dq += 4) {
          const float4 ev = *reinterpret_cast<const float4*>(&e_s[k][dq]);
          z[dq + 0] += ev.x; z[dq + 1] += ev.y;
          z[dq + 2] += ev.z; z[dq + 3] += ev.w;
        }
      }
    } else {
      for (int k = kmin; k < 64; ++k) {
        const float s = score_at(k);
        const bool valid = (k > lane) && (k <= kmax) && rowOk;
        const float e = valid ? __expf((s - mrow) * 0.015625f) : 0.f;
        rowsum += e;
#pragma unroll
        for (int dq = 0; dq < 64; dq += 4) {
          const float4 ev = *reinterpret_cast<const float4*>(&e_s[k][dq]);
          z[dq + 0] = fmaf(e, ev.x, z[dq + 0]);
          z[dq + 1] = fmaf(e, ev.y, z[dq + 1]);
          z[dq + 2] = fmaf(e, ev.z, z[dq + 2]);
          z[dq + 3] = fmaf(e, ev.w, z[dq + 3]);
        }
      }
    }

    // ---- d-term: lane j contributes rowsum_j * d[j][:]
#pragma unroll
    for (int dq = 0; dq < 64; ++dq)
      z[dq] = fmaf(rowsum, dT[dq][lane], z[dq]);

    // ---- denominator
    float tot = rowsum;
#pragma unroll
    for (int off = 32; off >= 1; off >>= 1) tot += __shfl_xor(tot, off);
    const float invtot = 1.0f / tot;

    // ---- cross-lane reduce z[d] over j-lanes; lane d keeps component d
    float zout = 0.f;
#pragma unroll
    for (int d = 0; d < 64; ++d) {
      float v = z[d];
#pragma unroll
      for (int off = 32; off >= 1; off >>= 1) v += __shfl_xor(v, off);
      if (lane == d) zout = v;
    }
    Z[((size_t)bi * SEQL + n * WIN + i) * (NH * DH) + h * DH + lane] = zout * invtot;
  }
}

// ---------------------------------------------------------------------------
extern "C" void kernel_launch(void* const* d_in, const int* in_sizes, int n_in,
                              void* d_out, int out_size, void* d_ws, size_t ws_size,
                              hipStream_t stream) {
  const float* x        = (const float*)d_in[0];
  const float* W_abcde  = (const float*)d_in[1];
  const float* b_abcde  = (const float*)d_in[2];
  const float* W_O      = (const float*)d_in[3];
  const float* b_O      = (const float*)d_in[4];
  float* out = (float*)d_out;

  float* Y = (float*)d_ws;                       // [2048][3840]
  float* Z = Y + (size_t)(BSZ * SEQL) * NCOL;    // [2048][768]

  const int M = BSZ * SEQL;  // 2048

  dim3 g1(NCOL / 128, M / 128);
  gemm_bias_kernel<128, 128, 8><<<g1, 256, 0, stream>>>(x, W_abcde, b_abcde, Y, M, NCOL, DMODEL);

  dim3 ga(NW, BSZ * NH);
  attn_kernel<<<ga, 256, 0, stream>>>(Y, Z);

  dim3 g2(DMODEL / 128, M / 128);
  gemm_bias_kernel<128, 128, 8><<<g2, 256, 0, stream>>>(Z, W_O, b_O, out, M, DMODEL, NH * DH);
}

// Round 2
// 417.077 us; speedup vs baseline: 4.5203x; 4.5203x over previous
//
#include <hip/hip_runtime.h>
#include <math.h>

#define NH     12
#define DH     64
#define WIN    32
#define SEQL   1024
#define BSZ    2
#define NW     (SEQL / WIN)       // 32
#define DMODEL 768
#define NCOL   (5 * NH * DH)      // 3840

typedef __attribute__((ext_vector_type(4))) float f32x4;
typedef __attribute__((ext_vector_type(8))) short bf16x8;

static __device__ __forceinline__ unsigned short f2bf(float f) {
  union { float f; unsigned u; } v; v.f = f;
  unsigned r = v.u + 0x7fffu + ((v.u >> 16) & 1u);
  return (unsigned short)(r >> 16);
}

// ---------------------------------------------------------------------------
// fp32 tiled GEMM with bias (unchanged from round 1 — passes, ~190us combined)
// ---------------------------------------------------------------------------
template<int BM, int BN, int BK>
__global__ __launch_bounds__(256)
void gemm_bias_kernel(const float* __restrict__ A, const float* __restrict__ B,
                      const float* __restrict__ bias, float* __restrict__ C,
                      int M, int N, int K) {
  __shared__ float As[BK][BM];
  __shared__ float Bs[BK][BN];
  const int tid = threadIdx.x;
  const int bm = blockIdx.y * BM;
  const int bn = blockIdx.x * BN;
  const int tm = (tid >> 4) << 3;
  const int tn = (tid & 15) << 3;
  float acc[8][8] = {};
  for (int k0 = 0; k0 < K; k0 += BK) {
    {
      const int m  = tid >> 1;
      const int kq = (tid & 1) << 2;
      const float4 v = *reinterpret_cast<const float4*>(&A[(size_t)(bm + m) * K + k0 + kq]);
      As[kq + 0][m] = v.x; As[kq + 1][m] = v.y;
      As[kq + 2][m] = v.z; As[kq + 3][m] = v.w;
    }
    {
      const int kq = tid >> 5;
      const int nn = (tid & 31) << 2;
      *reinterpret_cast<float4*>(&Bs[kq][nn]) =
          *reinterpret_cast<const float4*>(&B[(size_t)(k0 + kq) * N + bn + nn]);
    }
    __syncthreads();
#pragma unroll
    for (int kk = 0; kk < BK; ++kk) {
      float ar[8], br[8];
      *reinterpret_cast<float4*>(&ar[0]) = *reinterpret_cast<const float4*>(&As[kk][tm]);
      *reinterpret_cast<float4*>(&ar[4]) = *reinterpret_cast<const float4*>(&As[kk][tm + 4]);
      *reinterpret_cast<float4*>(&br[0]) = *reinterpret_cast<const float4*>(&Bs[kk][tn]);
      *reinterpret_cast<float4*>(&br[4]) = *reinterpret_cast<const float4*>(&Bs[kk][tn + 4]);
#pragma unroll
      for (int i = 0; i < 8; ++i)
#pragma unroll
        for (int j = 0; j < 8; ++j)
          acc[i][j] = fmaf(ar[i], br[j], acc[i][j]);
    }
    __syncthreads();
  }
#pragma unroll
  for (int i = 0; i < 8; ++i) {
#pragma unroll
    for (int j = 0; j < 8; ++j) {
      const int ncol = bn + tn + j;
      C[(size_t)(bm + tm + i) * N + ncol] = acc[i][j] + bias[ncol];
    }
  }
}

// ---------------------------------------------------------------------------
// MFMA trittention. One block per (window n, batch*head). 4 waves; wave w
// owns queries i = w*8..w*8+7. Per i: S_i[j][k] = sum_d a_j[d]*(c_i[d]*b_k[d])
// via 32x mfma_16x16x32_bf16 (A-frags static in regs; B-frags = c_i*b formed
// in regs). Wave holds full 64x64 S_i in accumulators -> in-lane mask/max/exp
// and both marginals r[j], q[k]. Marginals -> LDS [R|Q] (bf16). Final per
// block: Z[32][64] = [R|Q](32x128) @ [D;E](128x64) via 8 MFMA/wave using
// transposed DT/ET staged in LDS. Degenerate (n==0,i==0): r=1,q=1,tot=64.
// ---------------------------------------------------------------------------
__global__ __launch_bounds__(256, 2)
void attn_mfma_kernel(const float* __restrict__ Y, float* __restrict__ Z) {
  // padded to 136 cols (272B row stride): 16B-aligned rows, 8 words/bank b128
  __shared__ __align__(16) unsigned short DET[64][136];  // [d][0..63]=D^T, [d][64..127]=E^T
  __shared__ __align__(16) unsigned short RQ[32][136];   // [i][0..63]=r[j], [i][64..127]=q[k]
  __shared__ float tot_lds[32];

  const int n  = blockIdx.x;
  const int bh = blockIdx.y;
  const int bi = bh / NH;
  const int h  = bh % NH;
  const int tid  = threadIdx.x;
  const int wv   = tid >> 6;
  const int lane = tid & 63;
  const int m16  = lane & 15;
  const int g    = lane >> 4;
  const float* Yb = Y + (size_t)bi * SEQL * NCOL;

  // ---- stage D^T / E^T into LDS as bf16 (transpose during staging)
  {
    const int j = tid >> 2;          // look-around row 0..63
    const int q = tid & 3;           // 16-wide d chunk
    const int t = n * WIN - WIN + j;
    if (t >= 0) {
      const float* dr = Yb + (size_t)t * NCOL + (3 * NH + h) * DH + q * 16;
      const float* er = Yb + (size_t)t * NCOL + (4 * NH + h) * DH + q * 16;
#pragma unroll
      for (int e4 = 0; e4 < 16; e4 += 4) {
        const float4 vd = *reinterpret_cast<const float4*>(dr + e4);
        const float4 ve = *reinterpret_cast<const float4*>(er + e4);
        DET[q * 16 + e4 + 0][j] = f2bf(vd.x); DET[q * 16 + e4 + 1][j] = f2bf(vd.y);
        DET[q * 16 + e4 + 2][j] = f2bf(vd.z); DET[q * 16 + e4 + 3][j] = f2bf(vd.w);
        DET[q * 16 + e4 + 0][64 + j] = f2bf(ve.x); DET[q * 16 + e4 + 1][64 + j] = f2bf(ve.y);
        DET[q * 16 + e4 + 2][64 + j] = f2bf(ve.z); DET[q * 16 + e4 + 3][64 + j] = f2bf(ve.w);
      }
    } else {
#pragma unroll
      for (int e = 0; e < 16; ++e) {
        DET[q * 16 + e][j] = 0;
        DET[q * 16 + e][64 + j] = 0;
      }
    }
  }

  // ---- preload A-fragments (bf16, static per block) and b rows (fp32)
  // A-frag(jt,ks): lane holds A[jt*16+m16][ks*32+g*8 .. +7]
  bf16x8 afr[4][2];
#pragma unroll
  for (int jt = 0; jt < 4; ++jt) {
    const int j = jt * 16 + m16;
    const int t = n * WIN - WIN + j;
#pragma unroll
    for (int ks = 0; ks < 2; ++ks) {
      if (n == 0 && jt < 2) {
        bf16x8 z = {0, 0, 0, 0, 0, 0, 0, 0};
        afr[jt][ks] = z;
      } else {
        const float* p = Yb + (size_t)t * NCOL + h * DH + ks * 32 + g * 8;
        const float4 x0 = *reinterpret_cast<const float4*>(p);
        const float4 x1 = *reinterpret_cast<const float4*>(p + 4);
        bf16x8 a;
        a[0] = (short)f2bf(x0.x); a[1] = (short)f2bf(x0.y);
        a[2] = (short)f2bf(x0.z); a[3] = (short)f2bf(x0.w);
        a[4] = (short)f2bf(x1.x); a[5] = (short)f2bf(x1.y);
        a[6] = (short)f2bf(x1.z); a[7] = (short)f2bf(x1.w);
        afr[jt][ks] = a;
      }
    }
  }
  // b rows fp32: bfr[kt][ks][e] = b[kt*16+m16][ks*32+g*8+e]
  float bfr[4][2][8];
#pragma unroll
  for (int kt = 0; kt < 4; ++kt) {
    const int k = kt * 16 + m16;
    const int t = n * WIN - WIN + k;
#pragma unroll
    for (int ks = 0; ks < 2; ++ks) {
      if (n == 0 && kt < 2) {
#pragma unroll
        for (int e = 0; e < 8; ++e) bfr[kt][ks][e] = 0.f;
      } else {
        const float* p = Yb + (size_t)t * NCOL + (NH + h) * DH + ks * 32 + g * 8;
        const float4 x0 = *reinterpret_cast<const float4*>(p);
        const float4 x1 = *reinterpret_cast<const float4*>(p + 4);
        bfr[kt][ks][0] = x0.x; bfr[kt][ks][1] = x0.y; bfr[kt][ks][2] = x0.z; bfr[kt][ks][3] = x0.w;
        bfr[kt][ks][4] = x1.x; bfr[kt][ks][5] = x1.y; bfr[kt][ks][6] = x1.z; bfr[kt][ks][7] = x1.w;
      }
    }
  }

  const float NEG_INF = -__builtin_inff();
  const float* crow_base = Yb + (size_t)(n * WIN) * NCOL + (2 * NH + h) * DH;

  for (int ii = 0; ii < 8; ++ii) {
    const int i = wv * 8 + ii;
    const float* cp = crow_base + (size_t)i * NCOL;

    // c fragments (fp32, broadcast loads)
    float cf[2][8];
#pragma unroll
    for (int ks = 0; ks < 2; ++ks) {
      const float4 c0 = *reinterpret_cast<const float4*>(cp + ks * 32 + g * 8);
      const float4 c1 = *reinterpret_cast<const float4*>(cp + ks * 32 + g * 8 + 4);
      cf[ks][0] = c0.x; cf[ks][1] = c0.y; cf[ks][2] = c0.z; cf[ks][3] = c0.w;
      cf[ks][4] = c1.x; cf[ks][5] = c1.y; cf[ks][6] = c1.z; cf[ks][7] = c1.w;
    }

    f32x4 acc[4][4];
#pragma unroll
    for (int jt = 0; jt < 4; ++jt)
#pragma unroll
      for (int kt = 0; kt < 4; ++kt) {
        f32x4 z = {0.f, 0.f, 0.f, 0.f};
        acc[jt][kt] = z;
      }

    // S_i = A @ (c_i * B)^T : 32 MFMAs
#pragma unroll
    for (int ks = 0; ks < 2; ++ks) {
#pragma unroll
      for (int kt = 0; kt < 4; ++kt) {
        bf16x8 vf;
#pragma unroll
        for (int e = 0; e < 8; ++e) vf[e] = (short)f2bf(bfr[kt][ks][e] * cf[ks][e]);
#pragma unroll
        for (int jt = 0; jt < 4; ++jt)
          acc[jt][kt] = __builtin_amdgcn_mfma_f32_16x16x32_bf16(afr[jt][ks], vf, acc[jt][kt], 0, 0, 0);
      }
    }

    // ---- mask + global max (lane holds S[j= jt*16+g*4+r][k= kt*16+m16])
    float m = NEG_INF;
#pragma unroll
    for (int jt = 0; jt < 4; ++jt)
#pragma unroll
      for (int kt = 0; kt < 4; ++kt)
#pragma unroll
        for (int r = 0; r < 4; ++r) {
          const int j = jt * 16 + g * 4 + r;
          const int k = kt * 16 + m16;
          const bool valid = (k > j) && (k <= i + 32) && (n > 0 || j >= 32);
          const float s = valid ? acc[jt][kt][r] : NEG_INF;
          acc[jt][kt][r] = s;
          m = fmaxf(m, s);
        }
#pragma unroll
    for (int off = 32; off >= 1; off >>= 1) m = fmaxf(m, __shfl_xor(m, off));

    const bool degen = (n == 0 && i == 0);
    float rsel, qsel, tp;
    if (!degen) {
      // exp + in-lane partial marginals
      float rpf[16];
      float qp[4];
#pragma unroll
      for (int u = 0; u < 16; ++u) rpf[u] = 0.f;
#pragma unroll
      for (int u = 0; u < 4; ++u) qp[u] = 0.f;
#pragma unroll
      for (int jt = 0; jt < 4; ++jt)
#pragma unroll
        for (int kt = 0; kt < 4; ++kt)
#pragma unroll
          for (int r = 0; r < 4; ++r) {
            const float e = __expf((acc[jt][kt][r] - m) * 0.015625f);
            rpf[jt * 4 + r] += e;
            qp[kt] += e;
          }
      // r[j]: butterfly across m16 (low 4 bits)
#pragma unroll
      for (int u = 0; u < 16; ++u) {
        float v = rpf[u];
        v += __shfl_xor(v, 1); v += __shfl_xor(v, 2);
        v += __shfl_xor(v, 4); v += __shfl_xor(v, 8);
        rpf[u] = v;
      }
      // q[k]: butterfly across g (high 2 bits)
#pragma unroll
      for (int u = 0; u < 4; ++u) {
        float v = qp[u];
        v += __shfl_xor(v, 16); v += __shfl_xor(v, 32);
        qp[u] = v;
      }
      // total = sum_j r[j] (group partial + cross-group butterfly)
      float t = 0.f;
#pragma unroll
      for (int u = 0; u < 16; ++u) t += rpf[u];
      t += __shfl_xor(t, 16); t += __shfl_xor(t, 32);
      tp = t;
      // lane writes r[j] for j = (m16>>2)*16 + g*4 + (m16&3) -> rpf[m16] (static mux)
      float f8[8];
#pragma unroll
      for (int u = 0; u < 8; ++u) f8[u] = (m16 & 1) ? rpf[2 * u + 1] : rpf[2 * u];
      float f4s[4];
#pragma unroll
      for (int u = 0; u < 4; ++u) f4s[u] = (m16 & 2) ? f8[2 * u + 1] : f8[2 * u];
      float f2s[2];
#pragma unroll
      for (int u = 0; u < 2; ++u) f2s[u] = (m16 & 4) ? f4s[2 * u + 1] : f4s[2 * u];
      rsel = (m16 & 8) ? f2s[1] : f2s[0];
      // lane writes q[k] for k = g*16 + m16 -> qp[g] (static mux)
      const float q2a = (g & 1) ? qp[1] : qp[0];
      const float q2b = (g & 1) ? qp[3] : qp[2];
      qsel = (g & 2) ? q2b : q2a;
    } else {
      rsel = 1.f; qsel = 1.f; tp = 64.f;
    }

    RQ[i][(m16 >> 2) * 16 + g * 4 + (m16 & 3)] = f2bf(rsel);
    RQ[i][64 + g * 16 + m16] = f2bf(qsel);
    if (lane == 0) tot_lds[i] = tp;
  }

  __syncthreads();

  // ---- final GEMM: Z[32][64] = [R|Q] @ [D;E], wave wv owns d-tile nt = wv
  const int nt = wv;
  f32x4 zac[2];
  {
    f32x4 z = {0.f, 0.f, 0.f, 0.f};
    zac[0] = z; zac[1] = z;
  }
#pragma unroll
  for (int kq = 0; kq < 4; ++kq) {
    const bf16x8 bf = *reinterpret_cast<const bf16x8*>(&DET[nt * 16 + m16][kq * 32 + g * 8]);
#pragma unroll
    for (int mt = 0; mt < 2; ++mt) {
      const bf16x8 af = *reinterpret_cast<const bf16x8*>(&RQ[mt * 16 + m16][kq * 32 + g * 8]);
      zac[mt] = __builtin_amdgcn_mfma_f32_16x16x32_bf16(af, bf, zac[mt], 0, 0, 0);
    }
  }
#pragma unroll
  for (int mt = 0; mt < 2; ++mt)
#pragma unroll
    for (int r = 0; r < 4; ++r) {
      const int i = mt * 16 + g * 4 + r;
      const int d = nt * 16 + m16;
      const float inv = 1.0f / tot_lds[i];
      Z[((size_t)bi * SEQL + n * WIN + i) * (NH * DH) + h * DH + d] = zac[mt][r] * inv;
    }
}

// ---------------------------------------------------------------------------
extern "C" void kernel_launch(void* const* d_in, const int* in_sizes, int n_in,
                              void* d_out, int out_size, void* d_ws, size_t ws_size,
                              hipStream_t stream) {
  const float* x        = (const float*)d_in[0];
  const float* W_abcde  = (const float*)d_in[1];
  const float* b_abcde  = (const float*)d_in[2];
  const float* W_O      = (const float*)d_in[3];
  const float* b_O      = (const float*)d_in[4];
  float* out = (float*)d_out;

  float* Y = (float*)d_ws;                       // [2048][3840]
  float* Z = Y + (size_t)(BSZ * SEQL) * NCOL;    // [2048][768]

  const int M = BSZ * SEQL;  // 2048

  dim3 g1(NCOL / 128, M / 128);
  gemm_bias_kernel<128, 128, 8><<<g1, 256, 0, stream>>>(x, W_abcde, b_abcde, Y, M, NCOL, DMODEL);

  dim3 ga(NW, BSZ * NH);
  attn_mfma_kernel<<<ga, 256, 0, stream>>>(Y, Z);

  dim3 g2(DMODEL / 128, M / 128);
  gemm_bias_kernel<128, 128, 8><<<g2, 256, 0, stream>>>(Z, W_O, b_O, out, M, DMODEL, NH * DH);
}

// Round 3
// 174.609 us; speedup vs baseline: 10.7972x; 2.3886x over previous
//
#include <hip/hip_runtime.h>
#include <math.h>
#include <stdint.h>

#define NH     12
#define DH     64
#define WIN    32
#define SEQL   1024
#define BSZ    2
#define NW     (SEQL / WIN)       // 32
#define DMODEL 768
#define NCOL   (5 * NH * DH)      // 3840

typedef __attribute__((ext_vector_type(4))) float f32x4;
typedef __attribute__((ext_vector_type(8))) short bf16x8;
typedef unsigned short u16;

static __device__ __forceinline__ u16 f2bf(float f) {
  union { float f; unsigned u; } v; v.f = f;
  unsigned r = v.u + 0x7fffu + ((v.u >> 16) & 1u);
  return (u16)(r >> 16);
}
static __device__ __forceinline__ float bf2f(u16 u) {
  union { unsigned u; float f; } v; v.u = ((unsigned)u) << 16;
  return v.f;
}

typedef const __attribute__((address_space(1))) unsigned int* as1_cu32;
typedef __attribute__((address_space(3))) unsigned int* as3_u32;
static __device__ __forceinline__ void gload_lds16(const void* g, void* l) {
  __builtin_amdgcn_global_load_lds(
      reinterpret_cast<as1_cu32>(reinterpret_cast<uintptr_t>(g)),
      reinterpret_cast<as3_u32>(reinterpret_cast<uintptr_t>(l)), 16, 0, 0);
}

// ---------------------------------------------------------------------------
// fp32 -> bf16 straight conversion (x, n4 = n/4 float4 chunks)
// ---------------------------------------------------------------------------
__global__ __launch_bounds__(256)
void cvt_bf16_kernel(const float* __restrict__ S, u16* __restrict__ D, int n4) {
  const int i = blockIdx.x * 256 + threadIdx.x;
  if (i < n4) {
    const float4 v = reinterpret_cast<const float4*>(S)[i];
    ushort4 o;
    o.x = f2bf(v.x); o.y = f2bf(v.y); o.z = f2bf(v.z); o.w = f2bf(v.w);
    reinterpret_cast<ushort4*>(D)[i] = o;
  }
}

// ---------------------------------------------------------------------------
// fp32 [K][N] -> bf16 [N][K] transpose-convert, 64x64 tiles
// ---------------------------------------------------------------------------
__global__ __launch_bounds__(256)
void transpose_cvt_kernel(const float* __restrict__ S, u16* __restrict__ D,
                          int K, int N) {
  __shared__ u16 tile[64][68];   // tile[n_local][k_local]
  const int tid = threadIdx.x;
  const int n0 = blockIdx.x * 64;
  const int k0 = blockIdx.y * 64;
#pragma unroll
  for (int pass = 0; pass < 4; ++pass) {
    const int r = pass * 16 + (tid >> 4);   // k_local
    const int c = (tid & 15) << 2;          // n_local
    const float4 v = *reinterpret_cast<const float4*>(&S[(size_t)(k0 + r) * N + n0 + c]);
    tile[c + 0][r] = f2bf(v.x); tile[c + 1][r] = f2bf(v.y);
    tile[c + 2][r] = f2bf(v.z); tile[c + 3][r] = f2bf(v.w);
  }
  __syncthreads();
#pragma unroll
  for (int pass = 0; pass < 4; ++pass) {
    const int rn = pass * 16 + (tid >> 4);  // n_local
    const int ck = (tid & 15) << 2;         // k_local
    ushort4 o;
    o.x = tile[rn][ck + 0]; o.y = tile[rn][ck + 1];
    o.z = tile[rn][ck + 2]; o.w = tile[rn][ck + 3];
    *reinterpret_cast<ushort4*>(&D[(size_t)(n0 + rn) * K + k0 + ck]) = o;
  }
}

// ---------------------------------------------------------------------------
// bf16 MFMA GEMM: C[M][N] = A[M][K] @ Bt[N][K]^T + bias, out fp32 or bf16.
// BK=64; LDS staged via global_load_lds width-16 with XOR-swizzled SOURCE
// (slot ^= row&7) so frag ds_read_b128 is conflict-free (rule #21 pair).
// 4 waves in WAVES_M x WAVES_N grid; per wave MT x NT 16x16 frags.
// ---------------------------------------------------------------------------
template<int BM, int BN, int WAVES_M, int WAVES_N, bool OUT_BF16>
__global__ __launch_bounds__(256)
void gemm_mfma_kernel(const u16* __restrict__ A, const u16* __restrict__ Bt,
                      const float* __restrict__ bias, void* __restrict__ Cout,
                      int M, int N, int K) {
  constexpr int BK = 64;
  constexpr int MT = BM / (16 * WAVES_M);
  constexpr int NT = BN / (16 * WAVES_N);
  constexpr int CHA = BM / 8;   // 1KB staging chunks per operand
  constexpr int CHB = BN / 8;
  __shared__ __align__(16) u16 As[BM * BK];
  __shared__ __align__(16) u16 Bs[BN * BK];

  const int tid  = threadIdx.x;
  const int w    = tid >> 6;
  const int lane = tid & 63;
  const int m16  = lane & 15;
  const int g    = lane >> 4;
  const int wr   = w / WAVES_N;
  const int wc   = w % WAVES_N;
  const int bm   = blockIdx.y * BM;
  const int bn   = blockIdx.x * BN;

  // staging: lane covers LDS slot (row = ch*8 + lane>>3, slot = lane&7);
  // source col slot = (lane&7) ^ (lane>>3)  (8 u16 per slot)
  const int srow   = lane >> 3;
  const int srcCol = ((lane & 7) ^ srow) << 3;   // u16 units

  f32x4 acc[MT][NT];
#pragma unroll
  for (int i = 0; i < MT; ++i)
#pragma unroll
    for (int j = 0; j < NT; ++j) {
      f32x4 z = {0.f, 0.f, 0.f, 0.f};
      acc[i][j] = z;
    }

  for (int k0 = 0; k0 < K; k0 += BK) {
#pragma unroll
    for (int c = 0; c < CHA / 4; ++c) {
      const int ch = w * (CHA / 4) + c;
      const int r  = ch * 8 + srow;
      gload_lds16(A + (size_t)(bm + r) * K + k0 + srcCol, As + ch * 512);
    }
#pragma unroll
    for (int c = 0; c < CHB / 4; ++c) {
      const int ch = w * (CHB / 4) + c;
      const int r  = ch * 8 + srow;
      gload_lds16(Bt + (size_t)(bn + r) * K + k0 + srcCol, Bs + ch * 512);
    }
    __syncthreads();   // drains vmcnt (global_load_lds) + lgkm

#pragma unroll
    for (int kk = 0; kk < 2; ++kk) {
      const int cs = (((kk << 2) + g) ^ (m16 & 7)) << 3;  // swizzled col, u16
      bf16x8 af[MT], bf[NT];
#pragma unroll
      for (int i = 0; i < MT; ++i) {
        const int r = wr * (16 * MT) + i * 16 + m16;
        af[i] = *reinterpret_cast<const bf16x8*>(&As[r * 64 + cs]);
      }
#pragma unroll
      for (int j = 0; j < NT; ++j) {
        const int r = wc * (16 * NT) + j * 16 + m16;
        bf[j] = *reinterpret_cast<const bf16x8*>(&Bs[r * 64 + cs]);
      }
#pragma unroll
      for (int i = 0; i < MT; ++i)
#pragma unroll
        for (int j = 0; j < NT; ++j)
          acc[i][j] = __builtin_amdgcn_mfma_f32_16x16x32_bf16(af[i], bf[j], acc[i][j], 0, 0, 0);
    }
    __syncthreads();
  }

#pragma unroll
  for (int i = 0; i < MT; ++i) {
#pragma unroll
    for (int j = 0; j < NT; ++j) {
      const int col = bn + wc * 16 * NT + j * 16 + m16;
      const float bcol = bias[col];
#pragma unroll
      for (int rr = 0; rr < 4; ++rr) {
        const int row = bm + wr * 16 * MT + i * 16 + g * 4 + rr;
        const float v = acc[i][j][rr] + bcol;
        if (OUT_BF16)
          reinterpret_cast<u16*>(Cout)[(size_t)row * N + col] = f2bf(v);
        else
          reinterpret_cast<float*>(Cout)[(size_t)row * N + col] = v;
      }
    }
  }
}

// ---------------------------------------------------------------------------
// MFMA trittention (bf16 Y input, bf16 Z output). Structure verified R2.
// ---------------------------------------------------------------------------
__global__ __launch_bounds__(256, 2)
void attn_mfma_kernel(const u16* __restrict__ Y, u16* __restrict__ Z) {
  __shared__ __align__(16) u16 DET[64][136];  // [d][0..63]=D^T, [64..127]=E^T
  __shared__ __align__(16) u16 RQ[32][136];   // [i][0..63]=r[j], [64..127]=q[k]
  __shared__ float tot_lds[32];

  const int n  = blockIdx.x;
  const int bh = blockIdx.y;
  const int bi = bh / NH;
  const int h  = bh % NH;
  const int tid  = threadIdx.x;
  const int wv   = tid >> 6;
  const int lane = tid & 63;
  const int m16  = lane & 15;
  const int g    = lane >> 4;
  const u16* Yb = Y + (size_t)bi * SEQL * NCOL;

  // ---- stage D^T / E^T (transpose during staging, already bf16)
  {
    const int j = tid >> 2;
    const int q = tid & 3;
    const int t = n * WIN - WIN + j;
    if (t >= 0) {
      const u16* dr = Yb + (size_t)t * NCOL + (3 * NH + h) * DH + q * 16;
      const u16* er = Yb + (size_t)t * NCOL + (4 * NH + h) * DH + q * 16;
      const bf16x8 d0 = *reinterpret_cast<const bf16x8*>(dr);
      const bf16x8 d1 = *reinterpret_cast<const bf16x8*>(dr + 8);
      const bf16x8 e0 = *reinterpret_cast<const bf16x8*>(er);
      const bf16x8 e1 = *reinterpret_cast<const bf16x8*>(er + 8);
#pragma unroll
      for (int e = 0; e < 8; ++e) {
        DET[q * 16 + e][j]          = (u16)d0[e];
        DET[q * 16 + 8 + e][j]      = (u16)d1[e];
        DET[q * 16 + e][64 + j]     = (u16)e0[e];
        DET[q * 16 + 8 + e][64 + j] = (u16)e1[e];
      }
    } else {
#pragma unroll
      for (int e = 0; e < 16; ++e) {
        DET[q * 16 + e][j] = 0;
        DET[q * 16 + e][64 + j] = 0;
      }
    }
  }

  // ---- preload A-fragments (direct bf16) and b rows (bf16 -> fp32)
  bf16x8 afr[4][2];
#pragma unroll
  for (int jt = 0; jt < 4; ++jt) {
    const int j = jt * 16 + m16;
    const int t = n * WIN - WIN + j;
#pragma unroll
    for (int ks = 0; ks < 2; ++ks) {
      if (n == 0 && jt < 2) {
        bf16x8 z = {0, 0, 0, 0, 0, 0, 0, 0};
        afr[jt][ks] = z;
      } else {
        afr[jt][ks] = *reinterpret_cast<const bf16x8*>(
            Yb + (size_t)t * NCOL + h * DH + ks * 32 + g * 8);
      }
    }
  }
  float bfr[4][2][8];
#pragma unroll
  for (int kt = 0; kt < 4; ++kt) {
    const int k = kt * 16 + m16;
    const int t = n * WIN - WIN + k;
#pragma unroll
    for (int ks = 0; ks < 2; ++ks) {
      if (n == 0 && kt < 2) {
#pragma unroll
        for (int e = 0; e < 8; ++e) bfr[kt][ks][e] = 0.f;
      } else {
        const bf16x8 braw = *reinterpret_cast<const bf16x8*>(
            Yb + (size_t)t * NCOL + (NH + h) * DH + ks * 32 + g * 8);
#pragma unroll
        for (int e = 0; e < 8; ++e) bfr[kt][ks][e] = bf2f((u16)braw[e]);
      }
    }
  }

  const float NEG_INF = -__builtin_inff();
  const u16* crow_base = Yb + (size_t)(n * WIN) * NCOL + (2 * NH + h) * DH;

  for (int ii = 0; ii < 8; ++ii) {
    const int i = wv * 8 + ii;
    const u16* cp = crow_base + (size_t)i * NCOL;

    float cf[2][8];
#pragma unroll
    for (int ks = 0; ks < 2; ++ks) {
      const bf16x8 craw = *reinterpret_cast<const bf16x8*>(cp + ks * 32 + g * 8);
#pragma unroll
      for (int e = 0; e < 8; ++e) cf[ks][e] = bf2f((u16)craw[e]);
    }

    f32x4 acc[4][4];
#pragma unroll
    for (int jt = 0; jt < 4; ++jt)
#pragma unroll
      for (int kt = 0; kt < 4; ++kt) {
        f32x4 z = {0.f, 0.f, 0.f, 0.f};
        acc[jt][kt] = z;
      }

#pragma unroll
    for (int ks = 0; ks < 2; ++ks) {
#pragma unroll
      for (int kt = 0; kt < 4; ++kt) {
        bf16x8 vf;
#pragma unroll
        for (int e = 0; e < 8; ++e) vf[e] = (short)f2bf(bfr[kt][ks][e] * cf[ks][e]);
#pragma unroll
        for (int jt = 0; jt < 4; ++jt)
          acc[jt][kt] = __builtin_amdgcn_mfma_f32_16x16x32_bf16(afr[jt][ks], vf, acc[jt][kt], 0, 0, 0);
      }
    }

    // ---- mask + global max
    float m = NEG_INF;
#pragma unroll
    for (int jt = 0; jt < 4; ++jt)
#pragma unroll
      for (int kt = 0; kt < 4; ++kt)
#pragma unroll
        for (int r = 0; r < 4; ++r) {
          const int j = jt * 16 + g * 4 + r;
          const int k = kt * 16 + m16;
          const bool valid = (k > j) && (k <= i + 32) && (n > 0 || j >= 32);
          const float s = valid ? acc[jt][kt][r] : NEG_INF;
          acc[jt][kt][r] = s;
          m = fmaxf(m, s);
        }
#pragma unroll
    for (int off = 32; off >= 1; off >>= 1) m = fmaxf(m, __shfl_xor(m, off));

    const bool degen = (n == 0 && i == 0);
    float rsel, qsel, tp;
    if (!degen) {
      float rpf[16];
      float qp[4];
#pragma unroll
      for (int u = 0; u < 16; ++u) rpf[u] = 0.f;
#pragma unroll
      for (int u = 0; u < 4; ++u) qp[u] = 0.f;
#pragma unroll
      for (int jt = 0; jt < 4; ++jt)
#pragma unroll
        for (int kt = 0; kt < 4; ++kt)
#pragma unroll
          for (int r = 0; r < 4; ++r) {
            const float e = __expf((acc[jt][kt][r] - m) * 0.015625f);
            rpf[jt * 4 + r] += e;
            qp[kt] += e;
          }
#pragma unroll
      for (int u = 0; u < 16; ++u) {
        float v = rpf[u];
        v += __shfl_xor(v, 1); v += __shfl_xor(v, 2);
        v += __shfl_xor(v, 4); v += __shfl_xor(v, 8);
        rpf[u] = v;
      }
#pragma unroll
      for (int u = 0; u < 4; ++u) {
        float v = qp[u];
        v += __shfl_xor(v, 16); v += __shfl_xor(v, 32);
        qp[u] = v;
      }
      float t = 0.f;
#pragma unroll
      for (int u = 0; u < 16; ++u) t += rpf[u];
      t += __shfl_xor(t, 16); t += __shfl_xor(t, 32);
      tp = t;
      float f8[8];
#pragma unroll
      for (int u = 0; u < 8; ++u) f8[u] = (m16 & 1) ? rpf[2 * u + 1] : rpf[2 * u];
      float f4s[4];
#pragma unroll
      for (int u = 0; u < 4; ++u) f4s[u] = (m16 & 2) ? f8[2 * u + 1] : f8[2 * u];
      float f2s[2];
#pragma unroll
      for (int u = 0; u < 2; ++u) f2s[u] = (m16 & 4) ? f4s[2 * u + 1] : f4s[2 * u];
      rsel = (m16 & 8) ? f2s[1] : f2s[0];
      const float q2a = (g & 1) ? qp[1] : qp[0];
      const float q2b = (g & 1) ? qp[3] : qp[2];
      qsel = (g & 2) ? q2b : q2a;
    } else {
      rsel = 1.f; qsel = 1.f; tp = 64.f;
    }

    RQ[i][(m16 >> 2) * 16 + g * 4 + (m16 & 3)] = f2bf(rsel);
    RQ[i][64 + g * 16 + m16] = f2bf(qsel);
    if (lane == 0) tot_lds[i] = tp;
  }

  __syncthreads();

  // ---- final GEMM: Z[32][64] = [R|Q] @ [D;E]
  const int nt = wv;
  f32x4 zac[2];
  {
    f32x4 z = {0.f, 0.f, 0.f, 0.f};
    zac[0] = z; zac[1] = z;
  }
#pragma unroll
  for (int kq = 0; kq < 4; ++kq) {
    const bf16x8 bf = *reinterpret_cast<const bf16x8*>(&DET[nt * 16 + m16][kq * 32 + g * 8]);
#pragma unroll
    for (int mt = 0; mt < 2; ++mt) {
      const bf16x8 af = *reinterpret_cast<const bf16x8*>(&RQ[mt * 16 + m16][kq * 32 + g * 8]);
      zac[mt] = __builtin_amdgcn_mfma_f32_16x16x32_bf16(af, bf, zac[mt], 0, 0, 0);
    }
  }
#pragma unroll
  for (int mt = 0; mt < 2; ++mt)
#pragma unroll
    for (int r = 0; r < 4; ++r) {
      const int i = mt * 16 + g * 4 + r;
      const int d = nt * 16 + m16;
      const float inv = 1.0f / tot_lds[i];
      Z[((size_t)bi * SEQL + n * WIN + i) * (NH * DH) + h * DH + d] =
          f2bf(zac[mt][r] * inv);
    }
}

// ---------------------------------------------------------------------------
extern "C" void kernel_launch(void* const* d_in, const int* in_sizes, int n_in,
                              void* d_out, int out_size, void* d_ws, size_t ws_size,
                              hipStream_t stream) {
  const float* x        = (const float*)d_in[0];
  const float* W_abcde  = (const float*)d_in[1];
  const float* b_abcde  = (const float*)d_in[2];
  const float* W_O      = (const float*)d_in[3];
  const float* b_O      = (const float*)d_in[4];
  float* out = (float*)d_out;

  const int M = BSZ * SEQL;  // 2048

  u16* Yb  = (u16*)d_ws;                          // [2048][3840] bf16
  u16* xb  = Yb  + (size_t)M * NCOL;              // [2048][768]
  u16* Wt  = xb  + (size_t)M * DMODEL;            // [3840][768]
  u16* WOt = Wt  + (size_t)NCOL * DMODEL;         // [768][768]
  u16* Zb  = WOt + (size_t)(NH * DH) * DMODEL;    // [2048][768]

  cvt_bf16_kernel<<<(M * DMODEL / 4 + 255) / 256, 256, 0, stream>>>(x, xb, M * DMODEL / 4);
  transpose_cvt_kernel<<<dim3(NCOL / 64, DMODEL / 64), 256, 0, stream>>>(W_abcde, Wt, DMODEL, NCOL);
  transpose_cvt_kernel<<<dim3((NH * DH) / 64, DMODEL / 64), 256, 0, stream>>>(W_O, WOt, DMODEL, NH * DH);

  gemm_mfma_kernel<128, 128, 2, 2, true><<<dim3(NCOL / 128, M / 128), 256, 0, stream>>>(
      xb, Wt, b_abcde, Yb, M, NCOL, DMODEL);

  attn_mfma_kernel<<<dim3(NW, BSZ * NH), 256, 0, stream>>>(Yb, Zb);

  gemm_mfma_kernel<64, 64, 2, 2, false><<<dim3((NH * DH) / 64, M / 64), 256, 0, stream>>>(
      Zb, WOt, b_O, out, M, DMODEL, NH * DH);
}

// Round 4
// 161.672 us; speedup vs baseline: 11.6612x; 1.0800x over previous
//
#include <hip/hip_runtime.h>
#include <math.h>
#include <stdint.h>

#define NH     12
#define DH     64
#define WIN    32
#define SEQL   1024
#define BSZ    2
#define NW     (SEQL / WIN)       // 32
#define DMODEL 768
#define NCOL   (5 * NH * DH)      // 3840

typedef __attribute__((ext_vector_type(4))) float f32x4;
typedef __attribute__((ext_vector_type(8))) short bf16x8;
typedef unsigned short u16;

static __device__ __forceinline__ u16 f2bf(float f) {
  union { float f; unsigned u; } v; v.f = f;
  unsigned r = v.u + 0x7fffu + ((v.u >> 16) & 1u);
  return (u16)(r >> 16);
}
static __device__ __forceinline__ float bf2f(u16 u) {
  union { unsigned u; float f; } v; v.u = ((unsigned)u) << 16;
  return v.f;
}

typedef const __attribute__((address_space(1))) unsigned int* as1_cu32;
typedef __attribute__((address_space(3))) unsigned int* as3_u32;
static __device__ __forceinline__ void gload_lds16(const void* g, void* l) {
  __builtin_amdgcn_global_load_lds(
      reinterpret_cast<as1_cu32>(reinterpret_cast<uintptr_t>(g)),
      reinterpret_cast<as3_u32>(reinterpret_cast<uintptr_t>(l)), 16, 0, 0);
}

// ---------------------------------------------------------------------------
// fp32 -> bf16 straight conversion
// ---------------------------------------------------------------------------
__global__ __launch_bounds__(256)
void cvt_bf16_kernel(const float* __restrict__ S, u16* __restrict__ D, int n4) {
  const int i = blockIdx.x * 256 + threadIdx.x;
  if (i < n4) {
    const float4 v = reinterpret_cast<const float4*>(S)[i];
    ushort4 o;
    o.x = f2bf(v.x); o.y = f2bf(v.y); o.z = f2bf(v.z); o.w = f2bf(v.w);
    reinterpret_cast<ushort4*>(D)[i] = o;
  }
}

// ---------------------------------------------------------------------------
// fp32 [K][N] -> bf16 [N][K] transpose-convert, 64x64 tiles
// ---------------------------------------------------------------------------
__global__ __launch_bounds__(256)
void transpose_cvt_kernel(const float* __restrict__ S, u16* __restrict__ D,
                          int K, int N) {
  __shared__ u16 tile[64][68];
  const int tid = threadIdx.x;
  const int n0 = blockIdx.x * 64;
  const int k0 = blockIdx.y * 64;
#pragma unroll
  for (int pass = 0; pass < 4; ++pass) {
    const int r = pass * 16 + (tid >> 4);
    const int c = (tid & 15) << 2;
    const float4 v = *reinterpret_cast<const float4*>(&S[(size_t)(k0 + r) * N + n0 + c]);
    tile[c + 0][r] = f2bf(v.x); tile[c + 1][r] = f2bf(v.y);
    tile[c + 2][r] = f2bf(v.z); tile[c + 3][r] = f2bf(v.w);
  }
  __syncthreads();
#pragma unroll
  for (int pass = 0; pass < 4; ++pass) {
    const int rn = pass * 16 + (tid >> 4);
    const int ck = (tid & 15) << 2;
    ushort4 o;
    o.x = tile[rn][ck + 0]; o.y = tile[rn][ck + 1];
    o.z = tile[rn][ck + 2]; o.w = tile[rn][ck + 3];
    *reinterpret_cast<ushort4*>(&D[(size_t)(n0 + rn) * K + k0 + ck]) = o;
  }
}

// ---------------------------------------------------------------------------
// bf16 MFMA GEMM (unchanged from round 3 — verified)
// ---------------------------------------------------------------------------
template<int BM, int BN, int WAVES_M, int WAVES_N, bool OUT_BF16>
__global__ __launch_bounds__(256)
void gemm_mfma_kernel(const u16* __restrict__ A, const u16* __restrict__ Bt,
                      const float* __restrict__ bias, void* __restrict__ Cout,
                      int M, int N, int K) {
  constexpr int BK = 64;
  constexpr int MT = BM / (16 * WAVES_M);
  constexpr int NT = BN / (16 * WAVES_N);
  constexpr int CHA = BM / 8;
  constexpr int CHB = BN / 8;
  __shared__ __align__(16) u16 As[BM * BK];
  __shared__ __align__(16) u16 Bs[BN * BK];

  const int tid  = threadIdx.x;
  const int w    = tid >> 6;
  const int lane = tid & 63;
  const int m16  = lane & 15;
  const int g    = lane >> 4;
  const int wr   = w / WAVES_N;
  const int wc   = w % WAVES_N;
  const int bm   = blockIdx.y * BM;
  const int bn   = blockIdx.x * BN;

  const int srow   = lane >> 3;
  const int srcCol = ((lane & 7) ^ srow) << 3;

  f32x4 acc[MT][NT];
#pragma unroll
  for (int i = 0; i < MT; ++i)
#pragma unroll
    for (int j = 0; j < NT; ++j) {
      f32x4 z = {0.f, 0.f, 0.f, 0.f};
      acc[i][j] = z;
    }

  for (int k0 = 0; k0 < K; k0 += BK) {
#pragma unroll
    for (int c = 0; c < CHA / 4; ++c) {
      const int ch = w * (CHA / 4) + c;
      const int r  = ch * 8 + srow;
      gload_lds16(A + (size_t)(bm + r) * K + k0 + srcCol, As + ch * 512);
    }
#pragma unroll
    for (int c = 0; c < CHB / 4; ++c) {
      const int ch = w * (CHB / 4) + c;
      const int r  = ch * 8 + srow;
      gload_lds16(Bt + (size_t)(bn + r) * K + k0 + srcCol, Bs + ch * 512);
    }
    __syncthreads();

#pragma unroll
    for (int kk = 0; kk < 2; ++kk) {
      const int cs = (((kk << 2) + g) ^ (m16 & 7)) << 3;
      bf16x8 af[MT], bf[NT];
#pragma unroll
      for (int i = 0; i < MT; ++i) {
        const int r = wr * (16 * MT) + i * 16 + m16;
        af[i] = *reinterpret_cast<const bf16x8*>(&As[r * 64 + cs]);
      }
#pragma unroll
      for (int j = 0; j < NT; ++j) {
        const int r = wc * (16 * NT) + j * 16 + m16;
        bf[j] = *reinterpret_cast<const bf16x8*>(&Bs[r * 64 + cs]);
      }
#pragma unroll
      for (int i = 0; i < MT; ++i)
#pragma unroll
        for (int j = 0; j < NT; ++j)
          acc[i][j] = __builtin_amdgcn_mfma_f32_16x16x32_bf16(af[i], bf[j], acc[i][j], 0, 0, 0);
    }
    __syncthreads();
  }

#pragma unroll
  for (int i = 0; i < MT; ++i) {
#pragma unroll
    for (int j = 0; j < NT; ++j) {
      const int col = bn + wc * 16 * NT + j * 16 + m16;
      const float bcol = bias[col];
#pragma unroll
      for (int rr = 0; rr < 4; ++rr) {
        const int row = bm + wr * 16 * MT + i * 16 + g * 4 + rr;
        const float v = acc[i][j][rr] + bcol;
        if (OUT_BF16)
          reinterpret_cast<u16*>(Cout)[(size_t)row * N + col] = f2bf(v);
        else
          reinterpret_cast<float*>(Cout)[(size_t)row * N + col] = v;
      }
    }
  }
}

// ---------------------------------------------------------------------------
// MFMA trittention v2: 512 threads = 8 waves, 4 queries/wave.
// No max subtraction (exp2(s*log2e/64) safe: |s/64| ~ N(0,0.2), overflow at
// 88 is ~400 sigma). Reduce-scatter marginals (15+3 shuffles, kept index ==
// m16 / g matches RQ write mapping). Single barrier. bf16 operand regs.
// ---------------------------------------------------------------------------
__global__ __launch_bounds__(512, 3)
void attn_mfma_kernel(const u16* __restrict__ Y, u16* __restrict__ Z) {
  __shared__ __align__(16) u16 DET[64][136];  // [d][0..63]=D^T, [64..127]=E^T
  __shared__ __align__(16) u16 RQ[32][136];   // [i][0..63]=r[j], [64..127]=q[k]
  __shared__ float tot_lds[32];

  const int n  = blockIdx.x;
  const int bh = blockIdx.y;
  const int bi = bh / NH;
  const int h  = bh % NH;
  const int tid  = threadIdx.x;
  const int wv   = tid >> 6;      // 0..7
  const int lane = tid & 63;
  const int m16  = lane & 15;
  const int g    = lane >> 4;
  const u16* Yb = Y + (size_t)bi * SEQL * NCOL;

  // ---- stage D^T / E^T: wave wv writes dims [wv*8, wv*8+8), lane = j.
  // Writes: fixed row, consecutive j -> 2 lanes/dword = 2-way (free).
  {
    const int j  = lane;
    const int r8 = wv * 8;
    const int t  = n * WIN - WIN + j;
    if (t >= 0) {
      const bf16x8 dv = *reinterpret_cast<const bf16x8*>(
          Yb + (size_t)t * NCOL + (3 * NH + h) * DH + r8);
      const bf16x8 ev = *reinterpret_cast<const bf16x8*>(
          Yb + (size_t)t * NCOL + (4 * NH + h) * DH + r8);
#pragma unroll
      for (int e = 0; e < 8; ++e) {
        DET[r8 + e][j]      = (u16)dv[e];
        DET[r8 + e][64 + j] = (u16)ev[e];
      }
    } else {
#pragma unroll
      for (int e = 0; e < 8; ++e) {
        DET[r8 + e][j] = 0;
        DET[r8 + e][64 + j] = 0;
      }
    }
  }

  // ---- preload A-fragments and b rows (both bf16 in regs)
  bf16x8 afr[4][2], bfrb[4][2];
#pragma unroll
  for (int jt = 0; jt < 4; ++jt) {
    const int t = n * WIN - WIN + jt * 16 + m16;
#pragma unroll
    for (int ks = 0; ks < 2; ++ks) {
      if (n == 0 && jt < 2) {
        bf16x8 z = {0, 0, 0, 0, 0, 0, 0, 0};
        afr[jt][ks] = z;
        bfrb[jt][ks] = z;
      } else {
        afr[jt][ks] = *reinterpret_cast<const bf16x8*>(
            Yb + (size_t)t * NCOL + h * DH + ks * 32 + g * 8);
        bfrb[jt][ks] = *reinterpret_cast<const bf16x8*>(
            Yb + (size_t)t * NCOL + (NH + h) * DH + ks * 32 + g * 8);
      }
    }
  }

  const float K2 = 0.015625f * 1.44269504088896341f;  // log2(e)/64
  const u16* crow_base = Yb + (size_t)(n * WIN) * NCOL + (2 * NH + h) * DH;

  for (int ii = 0; ii < 4; ++ii) {
    const int i = wv * 4 + ii;
    const u16* cp = crow_base + (size_t)i * NCOL;

    bf16x8 craw[2];
    craw[0] = *reinterpret_cast<const bf16x8*>(cp + g * 8);
    craw[1] = *reinterpret_cast<const bf16x8*>(cp + 32 + g * 8);
    float cf[2][8];
#pragma unroll
    for (int ks = 0; ks < 2; ++ks)
#pragma unroll
      for (int e = 0; e < 8; ++e) cf[ks][e] = bf2f((u16)craw[ks][e]);

    f32x4 acc[4][4];
#pragma unroll
    for (int jt = 0; jt < 4; ++jt)
#pragma unroll
      for (int kt = 0; kt < 4; ++kt) {
        f32x4 z = {0.f, 0.f, 0.f, 0.f};
        acc[jt][kt] = z;
      }

    // S_i = A @ (c_i * B)^T : 32 MFMAs
#pragma unroll
    for (int ks = 0; ks < 2; ++ks) {
#pragma unroll
      for (int kt = 0; kt < 4; ++kt) {
        bf16x8 vf;
#pragma unroll
        for (int e = 0; e < 8; ++e)
          vf[e] = (short)f2bf(bf2f((u16)bfrb[kt][ks][e]) * cf[ks][e]);
#pragma unroll
        for (int jt = 0; jt < 4; ++jt)
          acc[jt][kt] = __builtin_amdgcn_mfma_f32_16x16x32_bf16(afr[jt][ks], vf, acc[jt][kt], 0, 0, 0);
      }
    }

    // ---- exp (no max-sub) + masked in-lane marginal partials
    float rp[16], qp[4];
#pragma unroll
    for (int u = 0; u < 16; ++u) rp[u] = 0.f;
#pragma unroll
    for (int u = 0; u < 4; ++u) qp[u] = 0.f;
#pragma unroll
    for (int kt = 0; kt < 4; ++kt) {
      const int k = kt * 16 + m16;
      const bool ck = k <= i + 32;
#pragma unroll
      for (int jt = 0; jt < 4; ++jt) {
        const bool rok = (n > 0) || (jt >= 2);
#pragma unroll
        for (int r = 0; r < 4; ++r) {
          const int j = jt * 16 + g * 4 + r;
          const bool valid = ck && rok && (k > j);
          const float e = valid ? exp2f(acc[jt][kt][r] * K2) : 0.f;
          rp[jt * 4 + r] += e;
          qp[kt] += e;
        }
      }
    }

    float rsel, qsel, tp;
    if (n == 0 && i == 0) {
      rsel = 1.f; qsel = 1.f; tp = 64.f;   // degenerate: uniform over 4096
    } else {
      // total (starts early, overlaps with scatters)
      float tin = (qp[0] + qp[1]) + (qp[2] + qp[3]);
#pragma unroll
      for (int off = 1; off <= 32; off <<= 1) tin += __shfl_xor(tin, off);
      tp = tin;

      // reduce-scatter rp[16] -> rsel (kept index == m16)
      float v8[8];
      {
        const bool b = (m16 & 1) != 0;
#pragma unroll
        for (int t2 = 0; t2 < 8; ++t2) {
          const float keep = b ? rp[2 * t2 + 1] : rp[2 * t2];
          const float send = b ? rp[2 * t2] : rp[2 * t2 + 1];
          v8[t2] = keep + __shfl_xor(send, 1);
        }
      }
      float v4s[4];
      {
        const bool b = (m16 & 2) != 0;
#pragma unroll
        for (int t2 = 0; t2 < 4; ++t2) {
          const float keep = b ? v8[2 * t2 + 1] : v8[2 * t2];
          const float send = b ? v8[2 * t2] : v8[2 * t2 + 1];
          v4s[t2] = keep + __shfl_xor(send, 2);
        }
      }
      float v2s[2];
      {
        const bool b = (m16 & 4) != 0;
#pragma unroll
        for (int t2 = 0; t2 < 2; ++t2) {
          const float keep = b ? v4s[2 * t2 + 1] : v4s[2 * t2];
          const float send = b ? v4s[2 * t2] : v4s[2 * t2 + 1];
          v2s[t2] = keep + __shfl_xor(send, 4);
        }
      }
      {
        const bool b = (m16 & 8) != 0;
        const float keep = b ? v2s[1] : v2s[0];
        const float send = b ? v2s[0] : v2s[1];
        rsel = keep + __shfl_xor(send, 8);
      }
      // reduce-scatter qp[4] -> qsel (kept index == g)
      float q2[2];
      {
        const bool b = (g & 1) != 0;
#pragma unroll
        for (int t2 = 0; t2 < 2; ++t2) {
          const float keep = b ? qp[2 * t2 + 1] : qp[2 * t2];
          const float send = b ? qp[2 * t2] : qp[2 * t2 + 1];
          q2[t2] = keep + __shfl_xor(send, 16);
        }
      }
      {
        const bool b = (g & 2) != 0;
        const float keep = b ? q2[1] : q2[0];
        const float send = b ? q2[0] : q2[1];
        qsel = keep + __shfl_xor(send, 32);
      }
    }

    RQ[i][(m16 >> 2) * 16 + g * 4 + (m16 & 3)] = f2bf(rsel);
    RQ[i][64 + g * 16 + m16] = f2bf(qsel);
    if (lane == 0) tot_lds[i] = tp;
  }

  __syncthreads();

  // ---- final GEMM: Z[32][64] = [R|Q] @ [D;E]; wave (mt=wv>>2, nt=wv&3)
  const int mt = wv >> 2;
  const int nt = wv & 3;
  f32x4 zac = {0.f, 0.f, 0.f, 0.f};
#pragma unroll
  for (int kq = 0; kq < 4; ++kq) {
    const bf16x8 bf = *reinterpret_cast<const bf16x8*>(&DET[nt * 16 + m16][kq * 32 + g * 8]);
    const bf16x8 af = *reinterpret_cast<const bf16x8*>(&RQ[mt * 16 + m16][kq * 32 + g * 8]);
    zac = __builtin_amdgcn_mfma_f32_16x16x32_bf16(af, bf, zac, 0, 0, 0);
  }
#pragma unroll
  for (int r = 0; r < 4; ++r) {
    const int i = mt * 16 + g * 4 + r;
    const int d = nt * 16 + m16;
    Z[((size_t)bi * SEQL + n * WIN + i) * (NH * DH) + h * DH + d] =
        f2bf(zac[r] / tot_lds[i]);
  }
}

// ---------------------------------------------------------------------------
extern "C" void kernel_launch(void* const* d_in, const int* in_sizes, int n_in,
                              void* d_out, int out_size, void* d_ws, size_t ws_size,
                              hipStream_t stream) {
  const float* x        = (const float*)d_in[0];
  const float* W_abcde  = (const float*)d_in[1];
  const float* b_abcde  = (const float*)d_in[2];
  const float* W_O      = (const float*)d_in[3];
  const float* b_O      = (const float*)d_in[4];
  float* out = (float*)d_out;

  const int M = BSZ * SEQL;  // 2048

  u16* Yb  = (u16*)d_ws;                          // [2048][3840] bf16
  u16* xb  = Yb  + (size_t)M * NCOL;              // [2048][768]
  u16* Wt  = xb  + (size_t)M * DMODEL;            // [3840][768]
  u16* WOt = Wt  + (size_t)NCOL * DMODEL;         // [768][768]
  u16* Zb  = WOt + (size_t)(NH * DH) * DMODEL;    // [2048][768]

  cvt_bf16_kernel<<<(M * DMODEL / 4 + 255) / 256, 256, 0, stream>>>(x, xb, M * DMODEL / 4);
  transpose_cvt_kernel<<<dim3(NCOL / 64, DMODEL / 64), 256, 0, stream>>>(W_abcde, Wt, DMODEL, NCOL);
  transpose_cvt_kernel<<<dim3((NH * DH) / 64, DMODEL / 64), 256, 0, stream>>>(W_O, WOt, DMODEL, NH * DH);

  gemm_mfma_kernel<128, 128, 2, 2, true><<<dim3(NCOL / 128, M / 128), 256, 0, stream>>>(
      xb, Wt, b_abcde, Yb, M, NCOL, DMODEL);

  attn_mfma_kernel<<<dim3(NW, BSZ * NH), 512, 0, stream>>>(Yb, Zb);

  gemm_mfma_kernel<64, 64, 2, 2, false><<<dim3((NH * DH) / 64, M / 64), 256, 0, stream>>>(
      Zb, WOt, b_O, out, M, DMODEL, NH * DH);
}

// Round 5
// 146.180 us; speedup vs baseline: 12.8971x; 1.1060x over previous
//
#include <hip/hip_runtime.h>
#include <math.h>
#include <stdint.h>

#define NH     12
#define DH     64
#define WIN    32
#define SEQL   1024
#define BSZ    2
#define NW     (SEQL / WIN)       // 32
#define DMODEL 768
#define NCOL   (5 * NH * DH)      // 3840

typedef __attribute__((ext_vector_type(4))) float f32x4;
typedef __attribute__((ext_vector_type(8))) short bf16x8;
typedef unsigned short u16;

static __device__ __forceinline__ u16 f2bf(float f) {
  union { float f; unsigned u; } v; v.f = f;
  unsigned r = v.u + 0x7fffu + ((v.u >> 16) & 1u);
  return (u16)(r >> 16);
}
static __device__ __forceinline__ float bf2f(u16 u) {
  union { unsigned u; float f; } v; v.u = ((unsigned)u) << 16;
  return v.f;
}
// D[15:0]=bf16(lo), D[31:16]=bf16(hi) — hw packed convert (RNE)
static __device__ __forceinline__ unsigned cvt_pk_bf16(float lo, float hi) {
  unsigned p;
  asm("v_cvt_pk_bf16_f32 %0, %1, %2" : "=v"(p) : "v"(lo), "v"(hi));
  return p;
}

typedef const __attribute__((address_space(1))) unsigned int* as1_cu32;
typedef __attribute__((address_space(3))) unsigned int* as3_u32;
static __device__ __forceinline__ void gload_lds16(const void* g, void* l) {
  __builtin_amdgcn_global_load_lds(
      reinterpret_cast<as1_cu32>(reinterpret_cast<uintptr_t>(g)),
      reinterpret_cast<as3_u32>(reinterpret_cast<uintptr_t>(l)), 16, 0, 0);
}

// ---------------------------------------------------------------------------
// Fused prep: [0,1536) cvt x->bf16; [1536,2256) transpose W_abcde;
// [2256,2400) transpose W_O.  One launch instead of three.
// ---------------------------------------------------------------------------
__global__ __launch_bounds__(256)
void prep_kernel(const float* __restrict__ x, const float* __restrict__ W,
                 const float* __restrict__ WO, u16* __restrict__ xb,
                 u16* __restrict__ Wt, u16* __restrict__ WOt) {
  __shared__ u16 tile[64][68];
  const int bid = blockIdx.x;
  const int tid = threadIdx.x;

  if (bid < 1536) {                      // ---- cvt x (2048*768 elems, x4)
    const int i = bid * 256 + tid;
    const float4 v = reinterpret_cast<const float4*>(x)[i];
    ushort4 o;
    o.x = f2bf(v.x); o.y = f2bf(v.y); o.z = f2bf(v.z); o.w = f2bf(v.w);
    reinterpret_cast<ushort4*>(xb)[i] = o;
    return;
  }

  const float* S; u16* D; int K, N, n0, k0;
  if (bid < 2256) {                      // ---- W_abcde [768][3840] -> [3840][768]
    const int b = bid - 1536;
    S = W; D = Wt; K = DMODEL; N = NCOL;
    n0 = (b % 60) * 64; k0 = (b / 60) * 64;
  } else {                               // ---- W_O [768][768] -> [768][768]
    const int b = bid - 2256;
    S = WO; D = WOt; K = DMODEL; N = NH * DH;
    n0 = (b % 12) * 64; k0 = (b / 12) * 64;
  }
#pragma unroll
  for (int pass = 0; pass < 4; ++pass) {
    const int r = pass * 16 + (tid >> 4);
    const int c = (tid & 15) << 2;
    const float4 v = *reinterpret_cast<const float4*>(&S[(size_t)(k0 + r) * N + n0 + c]);
    tile[c + 0][r] = f2bf(v.x); tile[c + 1][r] = f2bf(v.y);
    tile[c + 2][r] = f2bf(v.z); tile[c + 3][r] = f2bf(v.w);
  }
  __syncthreads();
#pragma unroll
  for (int pass = 0; pass < 4; ++pass) {
    const int rn = pass * 16 + (tid >> 4);
    const int ck = (tid & 15) << 2;
    ushort4 o;
    o.x = tile[rn][ck + 0]; o.y = tile[rn][ck + 1];
    o.z = tile[rn][ck + 2]; o.w = tile[rn][ck + 3];
    *reinterpret_cast<ushort4*>(&D[(size_t)(n0 + rn) * K + k0 + ck]) = o;
  }
}

// ---------------------------------------------------------------------------
// bf16 MFMA GEMM (verified R3/R4)
// ---------------------------------------------------------------------------
template<int BM, int BN, int WAVES_M, int WAVES_N, bool OUT_BF16>
__global__ __launch_bounds__(256)
void gemm_mfma_kernel(const u16* __restrict__ A, const u16* __restrict__ Bt,
                      const float* __restrict__ bias, void* __restrict__ Cout,
                      int M, int N, int K) {
  constexpr int BK = 64;
  constexpr int MT = BM / (16 * WAVES_M);
  constexpr int NT = BN / (16 * WAVES_N);
  constexpr int CHA = BM / 8;
  constexpr int CHB = BN / 8;
  __shared__ __align__(16) u16 As[BM * BK];
  __shared__ __align__(16) u16 Bs[BN * BK];

  const int tid  = threadIdx.x;
  const int w    = tid >> 6;
  const int lane = tid & 63;
  const int m16  = lane & 15;
  const int g    = lane >> 4;
  const int wr   = w / WAVES_N;
  const int wc   = w % WAVES_N;
  const int bm   = blockIdx.y * BM;
  const int bn   = blockIdx.x * BN;

  const int srow   = lane >> 3;
  const int srcCol = ((lane & 7) ^ srow) << 3;

  f32x4 acc[MT][NT];
#pragma unroll
  for (int i = 0; i < MT; ++i)
#pragma unroll
    for (int j = 0; j < NT; ++j) {
      f32x4 z = {0.f, 0.f, 0.f, 0.f};
      acc[i][j] = z;
    }

  for (int k0 = 0; k0 < K; k0 += BK) {
#pragma unroll
    for (int c = 0; c < CHA / 4; ++c) {
      const int ch = w * (CHA / 4) + c;
      const int r  = ch * 8 + srow;
      gload_lds16(A + (size_t)(bm + r) * K + k0 + srcCol, As + ch * 512);
    }
#pragma unroll
    for (int c = 0; c < CHB / 4; ++c) {
      const int ch = w * (CHB / 4) + c;
      const int r  = ch * 8 + srow;
      gload_lds16(Bt + (size_t)(bn + r) * K + k0 + srcCol, Bs + ch * 512);
    }
    __syncthreads();

#pragma unroll
    for (int kk = 0; kk < 2; ++kk) {
      const int cs = (((kk << 2) + g) ^ (m16 & 7)) << 3;
      bf16x8 af[MT], bf[NT];
#pragma unroll
      for (int i = 0; i < MT; ++i) {
        const int r = wr * (16 * MT) + i * 16 + m16;
        af[i] = *reinterpret_cast<const bf16x8*>(&As[r * 64 + cs]);
      }
#pragma unroll
      for (int j = 0; j < NT; ++j) {
        const int r = wc * (16 * NT) + j * 16 + m16;
        bf[j] = *reinterpret_cast<const bf16x8*>(&Bs[r * 64 + cs]);
      }
#pragma unroll
      for (int i = 0; i < MT; ++i)
#pragma unroll
        for (int j = 0; j < NT; ++j)
          acc[i][j] = __builtin_amdgcn_mfma_f32_16x16x32_bf16(af[i], bf[j], acc[i][j], 0, 0, 0);
    }
    __syncthreads();
  }

#pragma unroll
  for (int i = 0; i < MT; ++i) {
#pragma unroll
    for (int j = 0; j < NT; ++j) {
      const int col = bn + wc * 16 * NT + j * 16 + m16;
      const float bcol = bias[col];
#pragma unroll
      for (int rr = 0; rr < 4; ++rr) {
        const int row = bm + wr * 16 * MT + i * 16 + g * 4 + rr;
        const float v = acc[i][j][rr] + bcol;
        if (OUT_BF16)
          reinterpret_cast<u16*>(Cout)[(size_t)row * N + col] = f2bf(v);
        else
          reinterpret_cast<float*>(Cout)[(size_t)row * N + col] = v;
      }
    }
  }
}

// ---------------------------------------------------------------------------
// MFMA trittention v3. Static-dead jt>kt tiles dropped from MFMA (32->20
// per query) and exp pass (64->40 elems); k>j compare only on 4 diagonal
// tiles; K2=log2e/64 folded into cf; hw cvt_pk for B-frag; exp2 direct.
// ---------------------------------------------------------------------------
__global__ __launch_bounds__(512, 3)
void attn_mfma_kernel(const u16* __restrict__ Y, u16* __restrict__ Z) {
  __shared__ __align__(16) u16 DET[64][136];  // [d][0..63]=D^T, [64..127]=E^T
  __shared__ __align__(16) u16 RQ[32][136];   // [i][0..63]=r[j], [64..127]=q[k]
  __shared__ float tot_lds[32];

  const int n  = blockIdx.x;
  const int bh = blockIdx.y;
  const int bi = bh / NH;
  const int h  = bh % NH;
  const int tid  = threadIdx.x;
  const int wv   = tid >> 6;      // 0..7
  const int lane = tid & 63;
  const int m16  = lane & 15;
  const int g    = lane >> 4;
  const int g4   = g << 2;
  const u16* Yb = Y + (size_t)bi * SEQL * NCOL;

  // ---- stage D^T / E^T: wave wv writes dims [wv*8, wv*8+8), lane = j
  {
    const int j  = lane;
    const int r8 = wv * 8;
    const int t  = n * WIN - WIN + j;
    if (t >= 0) {
      const bf16x8 dv = *reinterpret_cast<const bf16x8*>(
          Yb + (size_t)t * NCOL + (3 * NH + h) * DH + r8);
      const bf16x8 ev = *reinterpret_cast<const bf16x8*>(
          Yb + (size_t)t * NCOL + (4 * NH + h) * DH + r8);
#pragma unroll
      for (int e = 0; e < 8; ++e) {
        DET[r8 + e][j]      = (u16)dv[e];
        DET[r8 + e][64 + j] = (u16)ev[e];
      }
    } else {
#pragma unroll
      for (int e = 0; e < 8; ++e) {
        DET[r8 + e][j] = 0;
        DET[r8 + e][64 + j] = 0;
      }
    }
  }

  // ---- preload A-fragments and b rows (bf16 regs)
  bf16x8 afr[4][2], bfrb[4][2];
#pragma unroll
  for (int jt = 0; jt < 4; ++jt) {
    const int t = n * WIN - WIN + jt * 16 + m16;
#pragma unroll
    for (int ks = 0; ks < 2; ++ks) {
      if (n == 0 && jt < 2) {
        bf16x8 z = {0, 0, 0, 0, 0, 0, 0, 0};
        afr[jt][ks] = z;
        bfrb[jt][ks] = z;
      } else {
        afr[jt][ks] = *reinterpret_cast<const bf16x8*>(
            Yb + (size_t)t * NCOL + h * DH + ks * 32 + g * 8);
        bfrb[jt][ks] = *reinterpret_cast<const bf16x8*>(
            Yb + (size_t)t * NCOL + (NH + h) * DH + ks * 32 + g * 8);
      }
    }
  }

  const float K2 = 0.015625f * 1.44269504088896341f;  // log2(e)/64
  const u16* crow_base = Yb + (size_t)(n * WIN) * NCOL + (2 * NH + h) * DH;

  for (int ii = 0; ii < 4; ++ii) {
    const int i = wv * 4 + ii;
    const u16* cp = crow_base + (size_t)i * NCOL;

    // cf = c * K2 (fp32)
    bf16x8 craw[2];
    craw[0] = *reinterpret_cast<const bf16x8*>(cp + g * 8);
    craw[1] = *reinterpret_cast<const bf16x8*>(cp + 32 + g * 8);
    float cf[2][8];
#pragma unroll
    for (int ks = 0; ks < 2; ++ks)
#pragma unroll
      for (int e = 0; e < 8; ++e) cf[ks][e] = bf2f((u16)craw[ks][e]) * K2;

    f32x4 acc[4][4];
#pragma unroll
    for (int kt = 0; kt < 4; ++kt)
#pragma unroll
      for (int jt = 0; jt <= kt; ++jt) {
        f32x4 z = {0.f, 0.f, 0.f, 0.f};
        acc[jt][kt] = z;
      }

    // S_i*K2 = A @ (c_i*K2 * B)^T : only jt<=kt tiles (20 MFMAs)
#pragma unroll
    for (int ks = 0; ks < 2; ++ks) {
#pragma unroll
      for (int kt = 0; kt < 4; ++kt) {
        bf16x8 vf;
#pragma unroll
        for (int e = 0; e < 8; e += 2) {
          const float lo = bf2f((u16)bfrb[kt][ks][e])     * cf[ks][e];
          const float hi = bf2f((u16)bfrb[kt][ks][e + 1]) * cf[ks][e + 1];
          reinterpret_cast<unsigned*>(&vf)[e >> 1] = cvt_pk_bf16(lo, hi);
        }
#pragma unroll
        for (int jt = 0; jt <= kt; ++jt)
          acc[jt][kt] = __builtin_amdgcn_mfma_f32_16x16x32_bf16(afr[jt][ks], vf, acc[jt][kt], 0, 0, 0);
      }
    }

    // ---- exp + masked marginal partials (upper-triangle tiles only)
    float rp[16], qp[4];
#pragma unroll
    for (int u = 0; u < 16; ++u) rp[u] = 0.f;
#pragma unroll
    for (int u = 0; u < 4; ++u) qp[u] = 0.f;
#pragma unroll
    for (int kt = 0; kt < 4; ++kt) {
      const bool ck = (kt < 2) ? true : (kt * 16 + m16 <= i + 32);
#pragma unroll
      for (int jt = 0; jt <= kt; ++jt) {
        const bool rok = (jt >= 2) || (n > 0);
        const bool base = ck && rok;
#pragma unroll
        for (int r = 0; r < 4; ++r) {
          const bool valid = (jt == kt) ? (base && (m16 > g4 + r)) : base;
          const float e = valid ? __builtin_amdgcn_exp2f(acc[jt][kt][r]) : 0.f;
          rp[jt * 4 + r] += e;
          qp[kt] += e;
        }
      }
    }

    float rsel, qsel, tp;
    if (n == 0 && i == 0) {
      rsel = 1.f; qsel = 1.f; tp = 64.f;   // degenerate: uniform over 4096
    } else {
      float tin = (qp[0] + qp[1]) + (qp[2] + qp[3]);
#pragma unroll
      for (int off = 1; off <= 32; off <<= 1) tin += __shfl_xor(tin, off);
      tp = tin;

      // reduce-scatter rp[16] -> rsel (kept index == m16)
      float v8[8];
      {
        const bool b = (m16 & 1) != 0;
#pragma unroll
        for (int t2 = 0; t2 < 8; ++t2) {
          const float keep = b ? rp[2 * t2 + 1] : rp[2 * t2];
          const float send = b ? rp[2 * t2] : rp[2 * t2 + 1];
          v8[t2] = keep + __shfl_xor(send, 1);
        }
      }
      float v4s[4];
      {
        const bool b = (m16 & 2) != 0;
#pragma unroll
        for (int t2 = 0; t2 < 4; ++t2) {
          const float keep = b ? v8[2 * t2 + 1] : v8[2 * t2];
          const float send = b ? v8[2 * t2] : v8[2 * t2 + 1];
          v4s[t2] = keep + __shfl_xor(send, 2);
        }
      }
      float v2s[2];
      {
        const bool b = (m16 & 4) != 0;
#pragma unroll
        for (int t2 = 0; t2 < 2; ++t2) {
          const float keep = b ? v4s[2 * t2 + 1] : v4s[2 * t2];
          const float send = b ? v4s[2 * t2] : v4s[2 * t2 + 1];
          v2s[t2] = keep + __shfl_xor(send, 4);
        }
      }
      {
        const bool b = (m16 & 8) != 0;
        const float keep = b ? v2s[1] : v2s[0];
        const float send = b ? v2s[0] : v2s[1];
        rsel = keep + __shfl_xor(send, 8);
      }
      // reduce-scatter qp[4] -> qsel (kept index == g)
      float q2[2];
      {
        const bool b = (g & 1) != 0;
#pragma unroll
        for (int t2 = 0; t2 < 2; ++t2) {
          const float keep = b ? qp[2 * t2 + 1] : qp[2 * t2];
          const float send = b ? qp[2 * t2] : qp[2 * t2 + 1];
          q2[t2] = keep + __shfl_xor(send, 16);
        }
      }
      {
        const bool b = (g & 2) != 0;
        const float keep = b ? q2[1] : q2[0];
        const float send = b ? q2[0] : q2[1];
        qsel = keep + __shfl_xor(send, 32);
      }
    }

    RQ[i][(m16 >> 2) * 16 + g4 + (m16 & 3)] = f2bf(rsel);
    RQ[i][64 + g * 16 + m16] = f2bf(qsel);
    if (lane == 0) tot_lds[i] = tp;
  }

  __syncthreads();

  // ---- final GEMM: Z[32][64] = [R|Q] @ [D;E]; wave (mt=wv>>2, nt=wv&3)
  const int mt = wv >> 2;
  const int nt = wv & 3;
  f32x4 zac = {0.f, 0.f, 0.f, 0.f};
#pragma unroll
  for (int kq = 0; kq < 4; ++kq) {
    const bf16x8 bf = *reinterpret_cast<const bf16x8*>(&DET[nt * 16 + m16][kq * 32 + g * 8]);
    const bf16x8 af = *reinterpret_cast<const bf16x8*>(&RQ[mt * 16 + m16][kq * 32 + g * 8]);
    zac = __builtin_amdgcn_mfma_f32_16x16x32_bf16(af, bf, zac, 0, 0, 0);
  }
#pragma unroll
  for (int r = 0; r < 4; ++r) {
    const int i = mt * 16 + g4 + r;
    const int d = nt * 16 + m16;
    const float inv = __builtin_amdgcn_rcpf(tot_lds[i]);
    Z[((size_t)bi * SEQL + n * WIN + i) * (NH * DH) + h * DH + d] =
        f2bf(zac[r] * inv);
  }
}

// ---------------------------------------------------------------------------
extern "C" void kernel_launch(void* const* d_in, const int* in_sizes, int n_in,
                              void* d_out, int out_size, void* d_ws, size_t ws_size,
                              hipStream_t stream) {
  const float* x        = (const float*)d_in[0];
  const float* W_abcde  = (const float*)d_in[1];
  const float* b_abcde  = (const float*)d_in[2];
  const float* W_O      = (const float*)d_in[3];
  const float* b_O      = (const float*)d_in[4];
  float* out = (float*)d_out;

  const int M = BSZ * SEQL;  // 2048

  u16* Yb  = (u16*)d_ws;                          // [2048][3840] bf16
  u16* xb  = Yb  + (size_t)M * NCOL;              // [2048][768]
  u16* Wt  = xb  + (size_t)M * DMODEL;            // [3840][768]
  u16* WOt = Wt  + (size_t)NCOL * DMODEL;         // [768][768]
  u16* Zb  = WOt + (size_t)(NH * DH) * DMODEL;    // [2048][768]

  prep_kernel<<<2400, 256, 0, stream>>>(x, W_abcde, W_O, xb, Wt, WOt);

  gemm_mfma_kernel<128, 128, 2, 2, true><<<dim3(NCOL / 128, M / 128), 256, 0, stream>>>(
      xb, Wt, b_abcde, Yb, M, NCOL, DMODEL);

  attn_mfma_kernel<<<dim3(NW, BSZ * NH), 512, 0, stream>>>(Yb, Zb);

  gemm_mfma_kernel<64, 64, 2, 2, false><<<dim3((NH * DH) / 64, M / 64), 256, 0, stream>>>(
      Zb, WOt, b_O, out, M, DMODEL, NH * DH);
}